// Round 1
// baseline (329.005 us; speedup 1.0000x reference)
//
#include <hip/hip_runtime.h>
#include <math.h>

// Problem constants (B, N, TF, DM) = (16, 4096, 512, 1024)
#define B_DIM 16
#define N_SEQ 4096
#define TF_DIM 512
#define DM_DIM 1024
#define CHUNK 128
#define NCHUNK (N_SEQ / CHUNK)   // 32
#define NKT (DM_DIM / 32)        // 32 K-steps of BK=32

typedef __attribute__((ext_vector_type(4))) float f32x4;
typedef __attribute__((ext_vector_type(8))) short bf16x8;

__device__ __forceinline__ unsigned short f2bf(float f) {
    // round-to-nearest-even fp32 -> bf16
    unsigned int u = __builtin_bit_cast(unsigned int, f);
    u += 0x7fffu + ((u >> 16) & 1u);
    return (unsigned short)(u >> 16);
}

// ---------------------------------------------------------------------------
// K1: u[m,f] = 2*x[m,f] - ( ls[m,:] . w[f,:] + bias[f] ),  m = b*N + n
// 128x128 tile, BK=32, 4 waves (2x2), mfma_f32_16x16x32_bf16,
// reg-staged fp32->bf16 conversion, double-buffered LDS, XOR bank swizzle.
// ---------------------------------------------------------------------------
__global__ __launch_bounds__(256, 2)
void gemm_u_kernel(const float* __restrict__ x,
                   const float* __restrict__ ls,
                   const float* __restrict__ wmat,
                   const float* __restrict__ bias,
                   float* __restrict__ u)
{
    __shared__ unsigned short As[2][4096];  // 128 rows x 32 k (bf16), swizzled
    __shared__ unsigned short Ws[2][4096];

    const int tid  = threadIdx.x;
    const int row0 = blockIdx.x * 128;   // over M = B*N
    const int f0   = blockIdx.y * 128;   // over TF

    const int lane = tid & 63;
    const int wid  = tid >> 6;
    const int wm = wid >> 1, wn = wid & 1;
    const int l15 = lane & 15, l4 = lane >> 4;

    // --- staging mapping: thread handles rows {srow, srow+64}, 8 k-elems each
    const int srow = tid >> 2;           // 0..63
    const int ke   = (tid & 3) * 8;      // 0,8,16,24
    const int sxor = (srow & 7) << 3;    // XOR swizzle (ushort units)
    const int sidx1 = (srow * 32 + ke) ^ sxor;
    const int sidx2 = ((srow + 64) * 32 + ke) ^ sxor;

    const float* aptr1 = ls   + (size_t)(row0 + srow) * DM_DIM + ke;
    const float* aptr2 = aptr1 + (size_t)64 * DM_DIM;
    const float* wptr1 = wmat + (size_t)(f0 + srow) * DM_DIM + ke;
    const float* wptr2 = wptr1 + (size_t)64 * DM_DIM;

    // --- fragment read offsets (ushort units), same XOR swizzle
    int rofa[4], rofw[4];
    const int rxor = (l15 & 7) << 3;
#pragma unroll
    for (int i = 0; i < 4; ++i) {
        rofa[i] = ((wm * 64 + i * 16 + l15) * 32 + l4 * 8) ^ rxor;
        rofw[i] = ((wn * 64 + i * 16 + l15) * 32 + l4 * 8) ^ rxor;
    }

    f32x4 acc[4][4];
#pragma unroll
    for (int i = 0; i < 4; ++i)
#pragma unroll
        for (int j = 0; j < 4; ++j) acc[i][j] = (f32x4){0.f, 0.f, 0.f, 0.f};

    f32x4 la[4], lw[4];  // in-flight staging registers

    auto load_step = [&](int kt) {
        const int ko = kt * 32;
        la[0] = *(const f32x4*)(aptr1 + ko);
        la[1] = *(const f32x4*)(aptr1 + ko + 4);
        la[2] = *(const f32x4*)(aptr2 + ko);
        la[3] = *(const f32x4*)(aptr2 + ko + 4);
        lw[0] = *(const f32x4*)(wptr1 + ko);
        lw[1] = *(const f32x4*)(wptr1 + ko + 4);
        lw[2] = *(const f32x4*)(wptr2 + ko);
        lw[3] = *(const f32x4*)(wptr2 + ko + 4);
    };

    auto write_lds = [&](int buf) {
        union { unsigned short s[8]; bf16x8 v; } p;
#pragma unroll
        for (int i = 0; i < 4; ++i) p.s[i] = f2bf(la[0][i]);
#pragma unroll
        for (int i = 0; i < 4; ++i) p.s[4 + i] = f2bf(la[1][i]);
        *(bf16x8*)(&As[buf][sidx1]) = p.v;
#pragma unroll
        for (int i = 0; i < 4; ++i) p.s[i] = f2bf(la[2][i]);
#pragma unroll
        for (int i = 0; i < 4; ++i) p.s[4 + i] = f2bf(la[3][i]);
        *(bf16x8*)(&As[buf][sidx2]) = p.v;
#pragma unroll
        for (int i = 0; i < 4; ++i) p.s[i] = f2bf(lw[0][i]);
#pragma unroll
        for (int i = 0; i < 4; ++i) p.s[4 + i] = f2bf(lw[1][i]);
        *(bf16x8*)(&Ws[buf][sidx1]) = p.v;
#pragma unroll
        for (int i = 0; i < 4; ++i) p.s[i] = f2bf(lw[2][i]);
#pragma unroll
        for (int i = 0; i < 4; ++i) p.s[4 + i] = f2bf(lw[3][i]);
        *(bf16x8*)(&Ws[buf][sidx2]) = p.v;
    };

    load_step(0);
    write_lds(0);
    __syncthreads();

    for (int kt = 0; kt < NKT; ++kt) {
        const int cur = kt & 1;
        if (kt + 1 < NKT) load_step(kt + 1);  // issue next-tile loads early

        const unsigned short* Ab = As[cur];
        const unsigned short* Wb = Ws[cur];
        bf16x8 af[4], wf[4];
#pragma unroll
        for (int i = 0; i < 4; ++i) {
            af[i] = *(const bf16x8*)(Ab + rofa[i]);
            wf[i] = *(const bf16x8*)(Wb + rofw[i]);
        }
#pragma unroll
        for (int mi = 0; mi < 4; ++mi)
#pragma unroll
            for (int ni = 0; ni < 4; ++ni)
                acc[mi][ni] = __builtin_amdgcn_mfma_f32_16x16x32_bf16(
                    af[mi], wf[ni], acc[mi][ni], 0, 0, 0);

        if (kt + 1 < NKT) write_lds((kt + 1) & 1);  // write after compute
        __syncthreads();
    }

    // epilogue: u = 2x - (acc + bias)
#pragma unroll
    for (int mi = 0; mi < 4; ++mi) {
#pragma unroll
        for (int j = 0; j < 4; ++j) {
            const int m = row0 + wm * 64 + mi * 16 + l4 * 4 + j;
            const size_t rb = (size_t)m * TF_DIM;
#pragma unroll
            for (int ni = 0; ni < 4; ++ni) {
                const int f = f0 + wn * 64 + ni * 16 + l15;
                const float seas = acc[mi][ni][j] + bias[f];
                u[rb + f] = 2.0f * x[rb + f] - seas;
            }
        }
    }
}

// ---------------------------------------------------------------------------
// K2: chunk-local EMA end value (zero carry-in):
//     e[b,ch,f] = sum_{j<CHUNK} a*c^(CHUNK-1-j) * u[b, ch*CHUNK+j, f]
// ---------------------------------------------------------------------------
__global__ __launch_bounds__(256)
void ema_chunk_end(const float* __restrict__ u, const float* __restrict__ alpha,
                   float* __restrict__ e)
{
    const int idx = blockIdx.x * 256 + threadIdx.x;  // (b*NCHUNK+ch)*TF + f
    const int f = idx & (TF_DIM - 1);
    const int bc = idx >> 9;
    const float a = 1.0f / (1.0f + expf(-alpha[0]));
    const float c = 1.0f - a;
    const float* up = u + (size_t)bc * CHUNK * TF_DIM + f;
    float acc = 0.0f;
#pragma unroll 8
    for (int j = 0; j < CHUNK; ++j)
        acc = fmaf(c, acc, a * up[(size_t)j * TF_DIM]);
    e[idx] = acc;
}

// ---------------------------------------------------------------------------
// K3: serial carry scan over chunks per (b,f):
//     carry[ch] = global EMA value at index ch*CHUNK-1 (carry-in of chunk ch)
// ---------------------------------------------------------------------------
__global__ __launch_bounds__(256)
void ema_carry(const float* __restrict__ e, const float* __restrict__ alpha,
               float* __restrict__ carry)
{
    const int idx = blockIdx.x * 256 + threadIdx.x;  // b*TF + f
    const int f = idx & (TF_DIM - 1);
    const int b = idx >> 9;
    const float a = 1.0f / (1.0f + expf(-alpha[0]));
    const float c = 1.0f - a;
    const float cC = exp2f((float)CHUNK * log2f(c));  // c^CHUNK (0 if c==0)
    const size_t base = (size_t)b * NCHUNK * TF_DIM + f;
    float Y = 0.0f;
    carry[base] = 0.0f;
    for (int ch = 1; ch < NCHUNK; ++ch) {
        Y = fmaf(cC, Y, e[base + (size_t)(ch - 1) * TF_DIM]);
        carry[base + (size_t)ch * TF_DIM] = Y;
    }
}

// ---------------------------------------------------------------------------
// K4: apply chunk-local EMA with carry-in, write final output
// ---------------------------------------------------------------------------
__global__ __launch_bounds__(256)
void ema_apply(const float* __restrict__ u, const float* __restrict__ carry,
               const float* __restrict__ alpha, float* __restrict__ out)
{
    const int idx = blockIdx.x * 256 + threadIdx.x;  // (b*NCHUNK+ch)*TF + f
    const int f = idx & (TF_DIM - 1);
    const int bc = idx >> 9;
    const float a = 1.0f / (1.0f + expf(-alpha[0]));
    const float c = 1.0f - a;
    float y = carry[idx];
    const float* up = u + (size_t)bc * CHUNK * TF_DIM + f;
    float* op = out + (size_t)bc * CHUNK * TF_DIM + f;
#pragma unroll 4
    for (int j = 0; j < CHUNK; ++j) {
        y = fmaf(c, y, a * up[(size_t)j * TF_DIM]);
        op[(size_t)j * TF_DIM] = y;
    }
}

extern "C" void kernel_launch(void* const* d_in, const int* in_sizes, int n_in,
                              void* d_out, int out_size, void* d_ws, size_t ws_size,
                              hipStream_t stream) {
    // setup_inputs order: x, latent_growth, latent_seasonal, alpha,
    //                     w_growth, b_growth, w_seasonal, b_seasonal
    const float* x     = (const float*)d_in[0];
    const float* ls    = (const float*)d_in[2];
    const float* alpha = (const float*)d_in[3];
    const float* wmat  = (const float*)d_in[6];
    const float* bias  = (const float*)d_in[7];
    float* out = (float*)d_out;

    float* u     = (float*)d_ws;                                   // 134 MB
    float* e     = u + (size_t)B_DIM * N_SEQ * TF_DIM;             // 1 MB
    float* carry = e + (size_t)B_DIM * NCHUNK * TF_DIM;            // 1 MB

    dim3 g1(B_DIM * N_SEQ / 128, TF_DIM / 128);  // (512, 4)
    gemm_u_kernel<<<g1, 256, 0, stream>>>(x, ls, wmat, bias, u);

    const int tot = B_DIM * NCHUNK * TF_DIM;  // 262144
    ema_chunk_end<<<tot / 256, 256, 0, stream>>>(u, alpha, e);
    ema_carry<<<(B_DIM * TF_DIM) / 256, 256, 0, stream>>>(e, alpha, carry);
    ema_apply<<<tot / 256, 256, 0, stream>>>(u, carry, alpha, out);
}

// Round 2
// 267.516 us; speedup vs baseline: 1.2299x; 1.2299x over previous
//
#include <hip/hip_runtime.h>
#include <math.h>

// Problem constants (B, N, TF, DM) = (16, 4096, 512, 1024)
#define B_DIM 16
#define N_SEQ 4096
#define TF_DIM 512
#define DM_DIM 1024
#define CHUNK 128
#define NCHUNK (N_SEQ / CHUNK)   // 32
#define NKT (DM_DIM / 32)        // 32 K-steps of BK=32

typedef __attribute__((ext_vector_type(4))) float f32x4;
typedef __attribute__((ext_vector_type(8))) short bf16x8;

__device__ __forceinline__ unsigned short f2bf(float f) {
    unsigned int u = __builtin_bit_cast(unsigned int, f);
    u += 0x7fffu + ((u >> 16) & 1u);
    return (unsigned short)(u >> 16);
}

// ---------------------------------------------------------------------------
// K1: u[m,f] = 2*x[m,f] - ( ls[m,:] . w[f,:] + bias[f] ),  m = b*N + n
// plus fused chunk-end EMA:  e[blockRow, f] = sum_j a*c^(127-j)*u[row0+j, f]
// 128x128 tile, BK=32, 4 waves (2x2), mfma_f32_16x16x32_bf16,
// DEPTH-2 register prefetch (two named staging sets), double-buffered LDS,
// XOR bank swizzle. Grid: x = f-block (fast) so A-panel is shared by
// adjacent dispatches and fetched from HBM once.
// ---------------------------------------------------------------------------
__global__ __launch_bounds__(256, 2)
void gemm_u_kernel(const float* __restrict__ x,
                   const float* __restrict__ ls,
                   const float* __restrict__ wmat,
                   const float* __restrict__ bias,
                   const float* __restrict__ alpha,
                   float* __restrict__ u,
                   float* __restrict__ e)
{
    __shared__ unsigned short As[2][4096];  // 128 rows x 32 k (bf16), swizzled
    __shared__ unsigned short Ws[2][4096];
    __shared__ float red[2][4][16];         // cross-wave e-reduction

    const int tid  = threadIdx.x;
    const int f0   = blockIdx.x * 128;   // over TF (fast dim)
    const int row0 = blockIdx.y * 128;   // over M = B*N; one (b,chunk) each

    const int lane = tid & 63;
    const int wid  = tid >> 6;
    const int wm = wid >> 1, wn = wid & 1;
    const int l15 = lane & 15, l4 = lane >> 4;

    // --- staging mapping: thread handles rows {srow, srow+64}, 8 k-elems each
    const int srow = tid >> 2;           // 0..63
    const int ke   = (tid & 3) * 8;      // 0,8,16,24
    const int sxor = (srow & 7) << 3;    // XOR swizzle (ushort units)
    const int sidx1 = (srow * 32 + ke) ^ sxor;
    const int sidx2 = ((srow + 64) * 32 + ke) ^ sxor;

    const float* aptr1 = ls   + (size_t)(row0 + srow) * DM_DIM + ke;
    const float* aptr2 = aptr1 + (size_t)64 * DM_DIM;
    const float* wptr1 = wmat + (size_t)(f0 + srow) * DM_DIM + ke;
    const float* wptr2 = wptr1 + (size_t)64 * DM_DIM;

    // --- fragment read offsets (ushort units), same XOR swizzle
    int rofa[4], rofw[4];
    const int rxor = (l15 & 7) << 3;
#pragma unroll
    for (int i = 0; i < 4; ++i) {
        rofa[i] = ((wm * 64 + i * 16 + l15) * 32 + l4 * 8) ^ rxor;
        rofw[i] = ((wn * 64 + i * 16 + l15) * 32 + l4 * 8) ^ rxor;
    }

    f32x4 acc[4][4];
#pragma unroll
    for (int i = 0; i < 4; ++i)
#pragma unroll
        for (int j = 0; j < 4; ++j) acc[i][j] = (f32x4){0.f, 0.f, 0.f, 0.f};

    // Two named staging sets (depth-2 prefetch; static names, no scratch)
    f32x4 A00, A01, A02, A03, W00, W01, W02, W03;
    f32x4 A10, A11, A12, A13, W10, W11, W12, W13;

#define LOAD_SET(SA, SW, KT) do {                                        \
        const int _ko = (KT) * 32;                                       \
        SA##0 = *(const f32x4*)(aptr1 + _ko);                            \
        SA##1 = *(const f32x4*)(aptr1 + _ko + 4);                        \
        SA##2 = *(const f32x4*)(aptr2 + _ko);                            \
        SA##3 = *(const f32x4*)(aptr2 + _ko + 4);                        \
        SW##0 = *(const f32x4*)(wptr1 + _ko);                            \
        SW##1 = *(const f32x4*)(wptr1 + _ko + 4);                        \
        SW##2 = *(const f32x4*)(wptr2 + _ko);                            \
        SW##3 = *(const f32x4*)(wptr2 + _ko + 4);                        \
    } while (0)

#define PACK8(V0, V1) ({                                                  \
        union { unsigned short s[8]; bf16x8 v; } _p;                     \
        _p.s[0] = f2bf(V0[0]); _p.s[1] = f2bf(V0[1]);                    \
        _p.s[2] = f2bf(V0[2]); _p.s[3] = f2bf(V0[3]);                    \
        _p.s[4] = f2bf(V1[0]); _p.s[5] = f2bf(V1[1]);                    \
        _p.s[6] = f2bf(V1[2]); _p.s[7] = f2bf(V1[3]);                    \
        _p.v; })

#define WRITE_SET(BUF, SA, SW) do {                                      \
        *(bf16x8*)(&As[BUF][sidx1]) = PACK8(SA##0, SA##1);               \
        *(bf16x8*)(&As[BUF][sidx2]) = PACK8(SA##2, SA##3);               \
        *(bf16x8*)(&Ws[BUF][sidx1]) = PACK8(SW##0, SW##1);               \
        *(bf16x8*)(&Ws[BUF][sidx2]) = PACK8(SW##2, SW##3);               \
    } while (0)

#define COMPUTE(BUF) do {                                                \
        const unsigned short* _Ab = As[BUF];                             \
        const unsigned short* _Wb = Ws[BUF];                             \
        bf16x8 _af[4], _wf[4];                                           \
        _Pragma("unroll")                                                \
        for (int i = 0; i < 4; ++i) {                                    \
            _af[i] = *(const bf16x8*)(_Ab + rofa[i]);                    \
            _wf[i] = *(const bf16x8*)(_Wb + rofw[i]);                    \
        }                                                                \
        _Pragma("unroll")                                                \
        for (int mi = 0; mi < 4; ++mi)                                   \
        _Pragma("unroll")                                                \
        for (int ni = 0; ni < 4; ++ni)                                   \
            acc[mi][ni] = __builtin_amdgcn_mfma_f32_16x16x32_bf16(       \
                _af[mi], _wf[ni], acc[mi][ni], 0, 0, 0);                 \
    } while (0)

    LOAD_SET(A0, W0, 0);
    LOAD_SET(A1, W1, 1);
    WRITE_SET(0, A0, W0);
    __syncthreads();

#pragma unroll 1
    for (int kt = 0; kt < NKT; kt += 2) {
        if (kt + 2 < NKT) LOAD_SET(A0, W0, kt + 2);   // issue 2 steps ahead
        COMPUTE(0);
        WRITE_SET(1, A1, W1);   // waits on loads issued a full phase ago
        __syncthreads();
        if (kt + 3 < NKT) LOAD_SET(A1, W1, kt + 3);
        COMPUTE(1);
        if (kt + 2 < NKT) WRITE_SET(0, A0, W0);
        __syncthreads();
    }

    // epilogue: u = 2x - (acc + bias); fused chunk-end EMA partial sums
    const float a = 1.0f / (1.0f + expf(-alpha[0]));
    const float c = 1.0f - a;
    const float l2c = log2f(c);

    float bia[4];
#pragma unroll
    for (int ni = 0; ni < 4; ++ni) bia[ni] = bias[f0 + wn * 64 + ni * 16 + l15];

    float epart[4] = {0.f, 0.f, 0.f, 0.f};

#pragma unroll
    for (int mi = 0; mi < 4; ++mi) {
#pragma unroll
        for (int j = 0; j < 4; ++j) {
            const int r = wm * 64 + mi * 16 + l4 * 4 + j;   // row in chunk, 0..127
            const size_t rb = (size_t)(row0 + r) * TF_DIM;
            const float wgt = (r == CHUNK - 1)
                                  ? a
                                  : a * exp2f((float)(CHUNK - 1 - r) * l2c);
#pragma unroll
            for (int ni = 0; ni < 4; ++ni) {
                const int f = f0 + wn * 64 + ni * 16 + l15;
                const float uval = 2.0f * x[rb + f] - (acc[mi][ni][j] + bia[ni]);
                u[rb + f] = uval;
                epart[ni] = fmaf(wgt, uval, epart[ni]);
            }
        }
    }

    // reduce over l4 (shuffle) then over wm (LDS)
#pragma unroll
    for (int ni = 0; ni < 4; ++ni) {
        epart[ni] += __shfl_xor(epart[ni], 16, 64);
        epart[ni] += __shfl_xor(epart[ni], 32, 64);
    }
    if (wm == 1 && l4 == 0) {
#pragma unroll
        for (int ni = 0; ni < 4; ++ni) red[wn][ni][l15] = epart[ni];
    }
    __syncthreads();
    if (wm == 0 && l4 == 0) {
#pragma unroll
        for (int ni = 0; ni < 4; ++ni) {
            const int f = f0 + wn * 64 + ni * 16 + l15;
            e[(size_t)blockIdx.y * TF_DIM + f] = epart[ni] + red[wn][ni][l15];
        }
    }
}

// ---------------------------------------------------------------------------
// K3: serial carry scan over chunks per (b,f):
//     carry[ch] = global EMA value at index ch*CHUNK-1 (carry-in of chunk ch)
// ---------------------------------------------------------------------------
__global__ __launch_bounds__(256)
void ema_carry(const float* __restrict__ e, const float* __restrict__ alpha,
               float* __restrict__ carry)
{
    const int idx = blockIdx.x * 256 + threadIdx.x;  // b*TF + f
    const int f = idx & (TF_DIM - 1);
    const int b = idx >> 9;
    const float a = 1.0f / (1.0f + expf(-alpha[0]));
    const float c = 1.0f - a;
    const float cC = exp2f((float)CHUNK * log2f(c));  // c^CHUNK
    const size_t base = (size_t)b * NCHUNK * TF_DIM + f;
    float Y = 0.0f;
    carry[base] = 0.0f;
    for (int ch = 1; ch < NCHUNK; ++ch) {
        Y = fmaf(cC, Y, e[base + (size_t)(ch - 1) * TF_DIM]);
        carry[base + (size_t)ch * TF_DIM] = Y;
    }
}

// ---------------------------------------------------------------------------
// K4: apply chunk-local EMA with carry-in, write final output
// ---------------------------------------------------------------------------
__global__ __launch_bounds__(256)
void ema_apply(const float* __restrict__ u, const float* __restrict__ carry,
               const float* __restrict__ alpha, float* __restrict__ out)
{
    const int idx = blockIdx.x * 256 + threadIdx.x;  // (b*NCHUNK+ch)*TF + f
    const int f = idx & (TF_DIM - 1);
    const int bc = idx >> 9;
    const float a = 1.0f / (1.0f + expf(-alpha[0]));
    const float c = 1.0f - a;
    float y = carry[idx];
    const float* up = u + (size_t)bc * CHUNK * TF_DIM + f;
    float* op = out + (size_t)bc * CHUNK * TF_DIM + f;
#pragma unroll 4
    for (int j = 0; j < CHUNK; ++j) {
        y = fmaf(c, y, a * up[(size_t)j * TF_DIM]);
        op[(size_t)j * TF_DIM] = y;
    }
}

extern "C" void kernel_launch(void* const* d_in, const int* in_sizes, int n_in,
                              void* d_out, int out_size, void* d_ws, size_t ws_size,
                              hipStream_t stream) {
    // setup_inputs order: x, latent_growth, latent_seasonal, alpha,
    //                     w_growth, b_growth, w_seasonal, b_seasonal
    const float* x     = (const float*)d_in[0];
    const float* ls    = (const float*)d_in[2];
    const float* alpha = (const float*)d_in[3];
    const float* wmat  = (const float*)d_in[6];
    const float* bias  = (const float*)d_in[7];
    float* out = (float*)d_out;

    float* u     = (float*)d_ws;                                   // 134 MB
    float* e     = u + (size_t)B_DIM * N_SEQ * TF_DIM;             // 1 MB
    float* carry = e + (size_t)B_DIM * NCHUNK * TF_DIM;            // 1 MB

    dim3 g1(TF_DIM / 128, B_DIM * N_SEQ / 128);  // (4, 512) f-block fast
    gemm_u_kernel<<<g1, 256, 0, stream>>>(x, ls, wmat, bias, alpha, u, e);

    const int tot = B_DIM * NCHUNK * TF_DIM;  // 262144
    ema_carry<<<(B_DIM * TF_DIM) / 256, 256, 0, stream>>>(e, alpha, carry);
    ema_apply<<<tot / 256, 256, 0, stream>>>(u, carry, alpha, out);
}